// Round 4
// baseline (304.516 us; speedup 1.0000x reference)
//
#include <hip/hip_runtime.h>
#include <hip/hip_bf16.h>
#include <stdint.h>

#define NNODES 10000
#define NEDGES 320000
#define DIM    256
#define KTOT   512
#define LN_EPS 1e-5f

typedef __attribute__((ext_vector_type(4))) float f32x4;
typedef __attribute__((ext_vector_type(8))) short bf16x8;

__device__ __forceinline__ ushort f2bf(float f) {
    union { float f; uint32_t u; } v; v.f = f;
    uint32_t r = v.u + 0x7fffu + ((v.u >> 16) & 1u);   // RNE
    return (ushort)(r >> 16);
}
__device__ __forceinline__ float bf2f(ushort u) {
    union { float f; uint32_t u; } v; v.u = ((uint32_t)u) << 16;
    return v.f;
}

// cast n4*4 floats -> bf16 (vectorized float4 -> ushort4)
__global__ void prep_cast(const float* __restrict__ src, ushort* __restrict__ dst, int n4) {
    int i = blockIdx.x * blockDim.x + threadIdx.x;
    if (i >= n4) return;
    float4 v = reinterpret_cast<const float4*>(src)[i];
    ushort4 o;
    o.x = f2bf(v.x); o.y = f2bf(v.y); o.z = f2bf(v.z); o.w = f2bf(v.w);
    reinterpret_cast<ushort4*>(dst)[i] = o;
}

// Edge W: Wa[h][kk][wc][nt][kg][ml][j] -> lane-linear frag reads (zero conflicts)
//   idx = h*65536 + kk*4096 + wc*2048 + nt*512 + kg*128 + ml*8 + j
//   = W_msg[kk*32+kg*8+j][h*128 + wc*64 + nt*16 + ml]
// Node W: Wua[kk][wc][nt][kg][ml][j]
//   idx = kk*8192 + wc*4096 + nt*512 + kg*128 + ml*8 + j
//   = W_upd[kk*32+kg*8+j][wc*128 + nt*16 + ml]
__global__ void prep_wt(const float* __restrict__ Wm, const float* __restrict__ Wu,
                        ushort* __restrict__ Wa, ushort* __restrict__ Wua) {
    int tid = blockIdx.x * blockDim.x + threadIdx.x;   // 262144 threads
    if (tid < 131072) {
        int h   = tid >> 16;
        int rem = tid & 65535;
        int kk  = rem >> 12;
        int wc  = (rem >> 11) & 1;
        int nt  = (rem >> 9) & 3;
        int kg  = (rem >> 7) & 3;
        int ml  = (rem >> 3) & 15;
        int j   = rem & 7;
        int k = kk * 32 + kg * 8 + j;
        int n = h * 128 + wc * 64 + nt * 16 + ml;
        Wa[tid] = f2bf(Wm[k * DIM + n]);
    } else {
        int rem = tid - 131072;
        int kk  = rem >> 13;
        int wc  = (rem >> 12) & 1;
        int nt  = (rem >> 9) & 7;
        int kg  = (rem >> 7) & 3;
        int ml  = (rem >> 3) & 15;
        int j   = rem & 7;
        int k = kk * 32 + kg * 8 + j;
        int n = wc * 128 + nt * 16 + ml;
        Wua[rem] = f2bf(Wu[k * DIM + n]);
    }
}

// ---- counting sort of edges by destination ----
__global__ void hist_k(const int* __restrict__ eidx, int* __restrict__ cnt) {
    int e = blockIdx.x * blockDim.x + threadIdx.x;
    if (e < NEDGES) atomicAdd(&cnt[eidx[NEDGES + e]], 1);
}

__global__ void scan_k(const int* __restrict__ cnt, int* __restrict__ cursor) {
    __shared__ int ts[256];
    int t = threadIdx.x;
    int base = t * 40;                       // 256*40 = 10240 >= NNODES
    int s = 0;
    for (int i = 0; i < 40; ++i) { int idx = base + i; if (idx < NNODES) s += cnt[idx]; }
    ts[t] = s;
    __syncthreads();
    int run = s;
    for (int off = 1; off < 256; off <<= 1) {   // Hillis-Steele inclusive scan
        int v = (t >= off) ? ts[t - off] : 0;
        __syncthreads();
        run += v;
        ts[t] = run;
        __syncthreads();
    }
    int o = run - s;                            // exclusive prefix
    for (int i = 0; i < 40; ++i) {
        int idx = base + i;
        if (idx < NNODES) { cursor[idx] = o; o += cnt[idx]; }
    }
}

__global__ void scatter_k(const int* __restrict__ eidx, int* __restrict__ cursor,
                          int* __restrict__ srow, int* __restrict__ sdst) {
    int e = blockIdx.x * blockDim.x + threadIdx.x;
    if (e >= NEDGES) return;
    int d = eidx[NEDGES + e];
    int r = eidx[e];
    int p = atomicAdd(&cursor[d], 1);
    srow[p] = r;
    sdst[p] = d;
}

// ---- edge message GEMM, barrier-free K-loop ----
// Grid: 625 edge-tiles x 2 col-halves. Block 512 thr = 8 waves; 512 edges x 128 cols.
// Wave (we=wave>>1, wc=wave&1): 128 edges (et=8) x 64 cols (nt=4); acc 128 VGPR.
#define EPREF(BUF, KN) do { \
    _Pragma("unroll") for (int et = 0; et < 8; ++et) { \
        uint o = ((KN) < 8 ? osrc[et] + (KN) * 32 : odst[et] + ((KN) - 8) * 32) + kg * 8; \
        BUF[et] = *reinterpret_cast<const bf16x8*>(xb + o); } } while (0)

#define ESTEP(BUF, KK) do { \
    _Pragma("unroll") for (int nt = 0; nt < 4; ++nt) { \
        bf16x8 b = *reinterpret_cast<const bf16x8*>(&smem[(KK) * 4096 + wc * 2048 + nt * 512 + lane * 8]); \
        _Pragma("unroll") for (int et = 0; et < 8; ++et) \
            acc[et][nt] = __builtin_amdgcn_mfma_f32_16x16x32_bf16(BUF[et], b, acc[et][nt], 0, 0, 0); } } while (0)

__global__ __launch_bounds__(512, 2)
void edge_gemm(const ushort* __restrict__ xb, const int* __restrict__ srow,
               const int* __restrict__ sdst, const ushort* __restrict__ Wa,
               const float* __restrict__ bmsg, float* __restrict__ agg) {
    __shared__ ushort smem[66048];   // Bs: 65536 (128KB W half) | Ds: 128 cols x 516 edges
    __shared__ int dstS[512];

    const int tid  = threadIdx.x;
    const int wave = tid >> 6, lane = tid & 63;
    const int ml = lane & 15, kg = lane >> 4;
    const int we = wave >> 1, wc = wave & 1;
    const int h     = blockIdx.x & 1;
    const int tile  = blockIdx.x >> 1;
    const int ebase = tile * 512;

    // per-lane A row byte... element offsets (uint, saves VGPR vs pointers)
    uint osrc[8], odst[8];
#pragma unroll
    for (int et = 0; et < 8; ++et) {
        int e = ebase + we * 128 + et * 16 + ml;
        osrc[et] = (uint)srow[e] * DIM;
        odst[et] = (uint)sdst[e] * DIM;
    }
    dstS[tid] = sdst[ebase + tid];

    bf16x8 a0[8], a1[8];
    EPREF(a0, 0);   // overlap first A-gather with W staging

    // stage W half into LDS: pure linear coalesced copy (Wa is pre-arranged)
    const ushort* wsrc = Wa + ((size_t)h << 16);
#pragma unroll
    for (int j = 0; j < 16; ++j) {
        int idx = j * 512 + tid;      // 16B chunk index
        *reinterpret_cast<int4*>(&smem[idx * 8]) =
            *reinterpret_cast<const int4*>(wsrc + idx * 8);
    }
    __syncthreads();

    f32x4 acc[8][4];
#pragma unroll
    for (int et = 0; et < 8; ++et)
#pragma unroll
        for (int nt = 0; nt < 4; ++nt) acc[et][nt] = (f32x4){0.f, 0.f, 0.f, 0.f};

#pragma unroll
    for (int kk = 0; kk < 16; ++kk) {
        if (kk & 1) { if (kk < 15) EPREF(a0, kk + 1); ESTEP(a1, kk); }
        else        { if (kk < 15) EPREF(a1, kk + 1); ESTEP(a0, kk); }
    }

    // ---- epilogue: bias+relu -> bf16 staging (reuse W LDS) -> segmented reduce ----
    __syncthreads();   // everyone done reading Bs
    const int hbase = h << 7;
#pragma unroll
    for (int nt = 0; nt < 4; ++nt) {
        const int c = wc * 64 + nt * 16 + ml;
        const float bb = bmsg[hbase + c];
#pragma unroll
        for (int et = 0; et < 8; ++et) {
            ushort4 pk;
#pragma unroll
            for (int i = 0; i < 4; ++i) {
                float v = acc[et][nt][i] + bb;
                v = v > 0.f ? v : 0.f;
                ((ushort*)&pk)[i] = f2bf(v);
            }
            *reinterpret_cast<ushort4*>(&smem[c * 516 + we * 128 + et * 16 + kg * 4]) = pk;
        }
    }
    __syncthreads();

    // segmented reduce, 4 edges per iteration (dst values are wave-uniform)
    const int c = tid & 127, q = tid >> 7;
    const int rbase = q * 128;
    float s = 0.f;
    int dprev = dstS[rbase];
    for (int i4 = 0; i4 < 32; ++i4) {
        int4 dd = *reinterpret_cast<const int4*>(&dstS[rbase + i4 * 4]);
        ushort4 vv = *reinterpret_cast<const ushort4*>(&smem[c * 516 + rbase + i4 * 4]);
        if (dd.x == dprev && dd.y == dprev && dd.z == dprev && dd.w == dprev) {
            s += bf2f(vv.x) + bf2f(vv.y) + bf2f(vv.z) + bf2f(vv.w);
        } else {
            int dj[4] = {dd.x, dd.y, dd.z, dd.w};
#pragma unroll
            for (int j = 0; j < 4; ++j) {
                if (dj[j] != dprev) {
                    if (s != 0.f) atomicAdd(&agg[(size_t)dprev * DIM + hbase + c], s);
                    s = 0.f; dprev = dj[j];
                }
                s += bf2f(((const ushort*)&vv)[j]);
            }
        }
    }
    if (s != 0.f) atomicAdd(&agg[(size_t)dprev * DIM + hbase + c], s);
}

#undef EPREF
#undef ESTEP

// ---- node update GEMM + bias + relu + LayerNorm ----
// Block 512 thr = 8 waves; 256 nodes x 256 cols. Wave (we=wave>>1, wc=wave&1):
// 64 nodes (et=4) x 128 cols (nt=8). W_upd staged in two 128KB LDS chunks.
// A: k<256 from xb (bf16); k>=256 from agg (fp32, cvt_pk in-register) -- no aggb pass.
__global__ __launch_bounds__(512, 2)
void node_gemm_ln(const ushort* __restrict__ xb, const float* __restrict__ agg,
                  const ushort* __restrict__ Wua, const float* __restrict__ bupd,
                  const float* __restrict__ gamma, const float* __restrict__ beta,
                  float* __restrict__ out) {
    __shared__ ushort Ws[65536];         // 128 KB W chunk
    __shared__ float pS[256][2][2];      // [node][wc][sum,ssq]

    const int tid  = threadIdx.x;
    const int wave = tid >> 6, lane = tid & 63;
    const int ml = lane & 15, kg = lane >> 4;
    const int we = wave >> 1, wc = wave & 1;
    const int nb = blockIdx.x * 256;

    uint arow[4];
#pragma unroll
    for (int et = 0; et < 4; ++et) {
        int n = nb + we * 64 + et * 16 + ml;
        arow[et] = (uint)(n < NNODES ? n : NNODES - 1) * DIM;
    }

    f32x4 acc[4][8];
#pragma unroll
    for (int et = 0; et < 4; ++et)
#pragma unroll
        for (int nt = 0; nt < 8; ++nt) acc[et][nt] = (f32x4){0.f, 0.f, 0.f, 0.f};

    // chunk 0: k in [0,256) -- A from xb
#pragma unroll
    for (int j = 0; j < 16; ++j) {
        int idx = j * 512 + tid;
        *reinterpret_cast<int4*>(&Ws[idx * 8]) = *reinterpret_cast<const int4*>(Wua + idx * 8);
    }
    __syncthreads();
#pragma unroll
    for (int kk = 0; kk < 8; ++kk) {
        bf16x8 a[4];
#pragma unroll
        for (int et = 0; et < 4; ++et)
            a[et] = *reinterpret_cast<const bf16x8*>(xb + arow[et] + kk * 32 + kg * 8);
#pragma unroll
        for (int nt = 0; nt < 8; ++nt) {
            bf16x8 b = *reinterpret_cast<const bf16x8*>(&Ws[kk * 8192 + wc * 4096 + nt * 512 + lane * 8]);
#pragma unroll
            for (int et = 0; et < 4; ++et)
                acc[et][nt] = __builtin_amdgcn_mfma_f32_16x16x32_bf16(a[et], b, acc[et][nt], 0, 0, 0);
        }
    }
    __syncthreads();

    // chunk 1: k in [256,512) -- A from agg (fp32 -> bf16 in-register)
#pragma unroll
    for (int j = 0; j < 16; ++j) {
        int idx = j * 512 + tid;
        *reinterpret_cast<int4*>(&Ws[idx * 8]) = *reinterpret_cast<const int4*>(Wua + 65536 + idx * 8);
    }
    __syncthreads();
#pragma unroll
    for (int kk = 0; kk < 8; ++kk) {
        bf16x8 a[4];
#pragma unroll
        for (int et = 0; et < 4; ++et) {
            float4 f0 = *reinterpret_cast<const float4*>(agg + arow[et] + kk * 32 + kg * 8);
            float4 f1 = *reinterpret_cast<const float4*>(agg + arow[et] + kk * 32 + kg * 8 + 4);
            union { bf16x8 v; __hip_bfloat162 h[4]; } u;
            u.h[0] = __float22bfloat162_rn(make_float2(f0.x, f0.y));
            u.h[1] = __float22bfloat162_rn(make_float2(f0.z, f0.w));
            u.h[2] = __float22bfloat162_rn(make_float2(f1.x, f1.y));
            u.h[3] = __float22bfloat162_rn(make_float2(f1.z, f1.w));
            a[et] = u.v;
        }
#pragma unroll
        for (int nt = 0; nt < 8; ++nt) {
            bf16x8 b = *reinterpret_cast<const bf16x8*>(&Ws[kk * 8192 + wc * 4096 + nt * 512 + lane * 8]);
#pragma unroll
            for (int et = 0; et < 4; ++et)
                acc[et][nt] = __builtin_amdgcn_mfma_f32_16x16x32_bf16(a[et], b, acc[et][nt], 0, 0, 0);
        }
    }

    // bias + relu, per-node partial sums over this wave's 128 cols
    float sum[4][4], ssq[4][4];
#pragma unroll
    for (int et = 0; et < 4; ++et)
#pragma unroll
        for (int i = 0; i < 4; ++i) { sum[et][i] = 0.f; ssq[et][i] = 0.f; }
#pragma unroll
    for (int nt = 0; nt < 8; ++nt) {
        const float bb = bupd[wc * 128 + nt * 16 + ml];
#pragma unroll
        for (int et = 0; et < 4; ++et)
#pragma unroll
            for (int i = 0; i < 4; ++i) {
                float v = acc[et][nt][i] + bb;
                v = v > 0.f ? v : 0.f;
                acc[et][nt][i] = v;
                sum[et][i] += v;
                ssq[et][i] += v * v;
            }
    }
#pragma unroll
    for (int m = 1; m < 16; m <<= 1) {
#pragma unroll
        for (int et = 0; et < 4; ++et)
#pragma unroll
            for (int i = 0; i < 4; ++i) {
                sum[et][i] += __shfl_xor(sum[et][i], m);
                ssq[et][i] += __shfl_xor(ssq[et][i], m);
            }
    }
    if (ml == 0) {
#pragma unroll
        for (int et = 0; et < 4; ++et)
#pragma unroll
            for (int i = 0; i < 4; ++i) {
                int nl = we * 64 + et * 16 + kg * 4 + i;
                pS[nl][wc][0] = sum[et][i];
                pS[nl][wc][1] = ssq[et][i];
            }
    }
    __syncthreads();

    float mu[4][4], rs[4][4];
#pragma unroll
    for (int et = 0; et < 4; ++et)
#pragma unroll
        for (int i = 0; i < 4; ++i) {
            int nl = we * 64 + et * 16 + kg * 4 + i;
            float S = pS[nl][0][0] + pS[nl][1][0];
            float Q = pS[nl][0][1] + pS[nl][1][1];
            float m = S * (1.f / 256.f);
            float var = Q * (1.f / 256.f) - m * m;
            mu[et][i] = m;
            rs[et][i] = rsqrtf(var + LN_EPS);
        }

#pragma unroll
    for (int nt = 0; nt < 8; ++nt) {
        const int cc = wc * 128 + nt * 16 + ml;
        const float g = gamma[cc], be = beta[cc];
#pragma unroll
        for (int et = 0; et < 4; ++et)
#pragma unroll
            for (int i = 0; i < 4; ++i) {
                int node = nb + we * 64 + et * 16 + kg * 4 + i;
                if (node < NNODES)
                    out[(size_t)node * DIM + cc] = (acc[et][nt][i] - mu[et][i]) * rs[et][i] * g + be;
            }
    }
}

extern "C" void kernel_launch(void* const* d_in, const int* in_sizes, int n_in,
                              void* d_out, int out_size, void* d_ws, size_t ws_size,
                              hipStream_t stream) {
    const float* x    = (const float*)d_in[0];
    const int*   eidx = (const int*)  d_in[1];
    const float* Wm   = (const float*)d_in[2];
    const float* bm   = (const float*)d_in[3];
    const float* Wu   = (const float*)d_in[4];
    const float* bu   = (const float*)d_in[5];
    const float* gam  = (const float*)d_in[6];
    const float* bet  = (const float*)d_in[7];
    float* out = (float*)d_out;

    char* ws = (char*)d_ws;
    float*  agg    = (float*) (ws);                    // 10,240,000 B
    ushort* xb     = (ushort*)(ws + 10240000);         //  5,120,000 B
    ushort* Wa     = (ushort*)(ws + 15360000);         //    262,144 B (edge W, arranged)
    ushort* Wua    = (ushort*)(ws + 15622144);         //    262,144 B (node W, arranged)
    int*    cnt    = (int*)   (ws + 15884288);         //     40,960 B
    int*    cursor = (int*)   (ws + 15925248);         //     40,960 B
    int*    srow   = (int*)   (ws + 15966208);         //  1,280,000 B
    int*    sdst   = (int*)   (ws + 17246208);         //  1,280,000 B

    hipMemsetAsync(agg, 0, (size_t)NNODES * DIM * sizeof(float), stream);
    hipMemsetAsync(cnt, 0, (size_t)NNODES * sizeof(int), stream);
    prep_cast<<<(NNODES * DIM / 4 + 255) / 256, 256, 0, stream>>>(x, xb, NNODES * DIM / 4);
    prep_wt<<<(2 * KTOT * DIM) / 256, 256, 0, stream>>>(Wm, Wu, Wa, Wua);
    hist_k<<<(NEDGES + 255) / 256, 256, 0, stream>>>(eidx, cnt);
    scan_k<<<1, 256, 0, stream>>>(cnt, cursor);
    scatter_k<<<(NEDGES + 255) / 256, 256, 0, stream>>>(eidx, cursor, srow, sdst);
    edge_gemm<<<2 * (NEDGES / 512), 512, 0, stream>>>(xb, srow, sdst, Wa, bm, agg);
    node_gemm_ln<<<(NNODES + 255) / 256, 512, 0, stream>>>(xb, agg, Wua, bu, gam, bet, out);
}

// Round 5
// 238.719 us; speedup vs baseline: 1.2756x; 1.2756x over previous
//
#include <hip/hip_runtime.h>
#include <hip/hip_bf16.h>
#include <stdint.h>

#define NNODES 10000
#define NEDGES 320000
#define DIM    256
#define KTOT   512
#define LN_EPS 1e-5f

typedef __attribute__((ext_vector_type(4))) float f32x4;
typedef __attribute__((ext_vector_type(8))) short bf16x8;

__device__ __forceinline__ ushort f2bf(float f) {
    union { float f; uint32_t u; } v; v.f = f;
    uint32_t r = v.u + 0x7fffu + ((v.u >> 16) & 1u);   // RNE
    return (ushort)(r >> 16);
}
__device__ __forceinline__ float bf2f(ushort u) {
    union { float f; uint32_t u; } v; v.u = ((uint32_t)u) << 16;
    return v.f;
}

// cast n4*4 floats -> bf16 (vectorized float4 -> ushort4)
__global__ void prep_cast(const float* __restrict__ src, ushort* __restrict__ dst, int n4) {
    int i = blockIdx.x * blockDim.x + threadIdx.x;
    if (i >= n4) return;
    float4 v = reinterpret_cast<const float4*>(src)[i];
    ushort4 o;
    o.x = f2bf(v.x); o.y = f2bf(v.y); o.z = f2bf(v.z); o.w = f2bf(v.w);
    reinterpret_cast<ushort4*>(dst)[i] = o;
}

// Edge W: Wa[h][kk][wc][nt][kg][ml][j]  (k-chunks of 4 kk are contiguous 16384-ushort spans)
//   idx = h*65536 + kk*4096 + wc*2048 + nt*512 + kg*128 + ml*8 + j
//   = W_msg[kk*32+kg*8+j][h*128 + wc*64 + nt*16 + ml]
// Node W: Wua[kk][nt16][kg][ml][j]   (nt16 = 0..15 over full 256 cols)
//   idx = kk*8192 + nt16*512 + kg*128 + ml*8 + j = W_upd[kk*32+kg*8+j][nt16*16 + ml]
__global__ void prep_wt(const float* __restrict__ Wm, const float* __restrict__ Wu,
                        ushort* __restrict__ Wa, ushort* __restrict__ Wua) {
    int tid = blockIdx.x * blockDim.x + threadIdx.x;   // 262144 threads
    if (tid < 131072) {
        int h   = tid >> 16;
        int rem = tid & 65535;
        int kk  = rem >> 12;
        int wc  = (rem >> 11) & 1;
        int nt  = (rem >> 9) & 3;
        int kg  = (rem >> 7) & 3;
        int ml  = (rem >> 3) & 15;
        int j   = rem & 7;
        int k = kk * 32 + kg * 8 + j;
        int n = h * 128 + wc * 64 + nt * 16 + ml;
        Wa[tid] = f2bf(Wm[k * DIM + n]);
    } else {
        int rem = tid - 131072;
        int kk  = rem >> 13;
        int nt  = (rem >> 9) & 15;
        int kg  = (rem >> 7) & 3;
        int ml  = (rem >> 3) & 15;
        int j   = rem & 7;
        int k = kk * 32 + kg * 8 + j;
        int n = nt * 16 + ml;
        Wua[rem] = f2bf(Wu[k * DIM + n]);
    }
}

// ---- counting sort of edges by destination ----
__global__ void hist_k(const int* __restrict__ eidx, int* __restrict__ cnt) {
    int e = blockIdx.x * blockDim.x + threadIdx.x;
    if (e < NEDGES) atomicAdd(&cnt[eidx[NEDGES + e]], 1);
}

__global__ void scan_k(const int* __restrict__ cnt, int* __restrict__ cursor) {
    __shared__ int ts[256];
    int t = threadIdx.x;
    int base = t * 40;                       // 256*40 = 10240 >= NNODES
    int s = 0;
    for (int i = 0; i < 40; ++i) { int idx = base + i; if (idx < NNODES) s += cnt[idx]; }
    ts[t] = s;
    __syncthreads();
    int run = s;
    for (int off = 1; off < 256; off <<= 1) {   // Hillis-Steele inclusive scan
        int v = (t >= off) ? ts[t - off] : 0;
        __syncthreads();
        run += v;
        ts[t] = run;
        __syncthreads();
    }
    int o = run - s;                            // exclusive prefix
    for (int i = 0; i < 40; ++i) {
        int idx = base + i;
        if (idx < NNODES) { cursor[idx] = o; o += cnt[idx]; }
    }
}

__global__ void scatter_k(const int* __restrict__ eidx, int* __restrict__ cursor,
                          int* __restrict__ srow, int* __restrict__ sdst) {
    int e = blockIdx.x * blockDim.x + threadIdx.x;
    if (e >= NEDGES) return;
    int d = eidx[NEDGES + e];
    int r = eidx[e];
    int p = atomicAdd(&cursor[d], 1);
    srow[p] = r;
    sdst[p] = d;
}

// ---- edge message GEMM ----
// Grid: 2500 edge-tiles(128) x 2 col-halves(128). Block 256 thr = 4 waves
// (we = edge group of 64, wc = col group of 64). Wave: 64 edges x 64 cols,
// acc[4][4] = 64 AGPR. W staged in four 32KB k-chunks; A 2-deep reg prefetch.
#define EPREF(BUF, KN) do { \
    _Pragma("unroll") for (int et = 0; et < 4; ++et) { \
        uint o = ((KN) < 8 ? osrc[et] + (KN) * 32 : odst[et] + ((KN) - 8) * 32) + kg * 8; \
        BUF[et] = *reinterpret_cast<const bf16x8*>(xb + o); } } while (0)

#define ESTEP(BUF, KL) do { \
    _Pragma("unroll") for (int nt = 0; nt < 4; ++nt) { \
        bf16x8 b = *reinterpret_cast<const bf16x8*>(&smem[(KL) * 4096 + wc * 2048 + nt * 512 + lane * 8]); \
        _Pragma("unroll") for (int et = 0; et < 4; ++et) \
            acc[et][nt] = __builtin_amdgcn_mfma_f32_16x16x32_bf16(BUF[et], b, acc[et][nt], 0, 0, 0); } } while (0)

__global__ __launch_bounds__(256, 3)
void edge_gemm(const ushort* __restrict__ xb, const int* __restrict__ srow,
               const int* __restrict__ sdst, const ushort* __restrict__ Wa,
               const float* __restrict__ bmsg, float* __restrict__ agg) {
    __shared__ ushort smem[16896];   // W chunk (16384) / Ds 128 cols x 132 stride
    __shared__ int dstS[128];

    const int tid  = threadIdx.x;
    const int wave = tid >> 6, lane = tid & 63;
    const int ml = lane & 15, kg = lane >> 4;
    const int we = wave >> 1, wc = wave & 1;
    const int h     = blockIdx.x & 1;
    const int tile  = blockIdx.x >> 1;
    const int ebase = tile * 128;

    uint osrc[4], odst[4];
#pragma unroll
    for (int et = 0; et < 4; ++et) {
        int e = ebase + we * 64 + et * 16 + ml;
        osrc[et] = (uint)srow[e] * DIM;
        odst[et] = (uint)sdst[e] * DIM;
    }
    if (tid < 128) dstS[tid] = sdst[ebase + tid];

    bf16x8 a0[4], a1[4];
    EPREF(a0, 0);
    EPREF(a1, 1);

    f32x4 acc[4][4];
#pragma unroll
    for (int et = 0; et < 4; ++et)
#pragma unroll
        for (int nt = 0; nt < 4; ++nt) acc[et][nt] = (f32x4){0.f, 0.f, 0.f, 0.f};

    const ushort* wsrc = Wa + ((size_t)h << 16);
#pragma unroll
    for (int p = 0; p < 4; ++p) {
        if (p) __syncthreads();                       // waves done reading prev chunk
        const ushort* ws = wsrc + p * 16384;
#pragma unroll
        for (int j = 0; j < 8; ++j) {
            int idx = j * 256 + tid;                  // 16B chunk index 0..2047
            *reinterpret_cast<int4*>(&smem[idx * 8]) =
                *reinterpret_cast<const int4*>(ws + idx * 8);
        }
        __syncthreads();
        const int kb = p * 4;                         // compile-time (p unrolled)
        ESTEP(a0, 0); if (kb + 0 < 14) EPREF(a0, kb + 2);
        ESTEP(a1, 1); if (kb + 1 < 14) EPREF(a1, kb + 3);
        ESTEP(a0, 2); if (kb + 2 < 14) EPREF(a0, kb + 4);
        ESTEP(a1, 3); if (kb + 3 < 14) EPREF(a1, kb + 5);
    }

    // ---- epilogue: bias+relu -> bf16 Ds[col][edge] -> segmented reduce ----
    __syncthreads();   // done reading W chunk 3
    const int hbase = h << 7;
#pragma unroll
    for (int nt = 0; nt < 4; ++nt) {
        const int c = wc * 64 + nt * 16 + ml;
        const float bb = bmsg[hbase + c];
#pragma unroll
        for (int et = 0; et < 4; ++et) {
            ushort4 pk;
#pragma unroll
            for (int i = 0; i < 4; ++i) {
                float v = acc[et][nt][i] + bb;
                v = v > 0.f ? v : 0.f;
                ((ushort*)&pk)[i] = f2bf(v);
            }
            *reinterpret_cast<ushort4*>(&smem[c * 132 + we * 64 + et * 16 + kg * 4]) = pk;
        }
    }
    __syncthreads();

    // segmented reduce: thread (c = tid&127, q = tid>>7) scans 64 sorted edges
    const int c = tid & 127, q = tid >> 7;
    const int rbase = q * 64;
    float s = 0.f;
    int dprev = dstS[rbase];
    for (int i4 = 0; i4 < 16; ++i4) {
        int4 dd = *reinterpret_cast<const int4*>(&dstS[rbase + i4 * 4]);
        ushort4 vv = *reinterpret_cast<const ushort4*>(&smem[c * 132 + rbase + i4 * 4]);
        if (dd.x == dprev && dd.y == dprev && dd.z == dprev && dd.w == dprev) {
            s += bf2f(vv.x) + bf2f(vv.y) + bf2f(vv.z) + bf2f(vv.w);
        } else {
            int dj[4] = {dd.x, dd.y, dd.z, dd.w};
#pragma unroll
            for (int j = 0; j < 4; ++j) {
                if (dj[j] != dprev) {
                    if (s != 0.f) atomicAdd(&agg[(size_t)dprev * DIM + hbase + c], s);
                    s = 0.f; dprev = dj[j];
                }
                s += bf2f(((const ushort*)&vv)[j]);
            }
        }
    }
    if (s != 0.f) atomicAdd(&agg[(size_t)dprev * DIM + hbase + c], s);
}

#undef EPREF
#undef ESTEP

// ---- node update GEMM + bias + relu + LayerNorm ----
// 625 single-wave blocks; wave = 16 nodes x 256 cols, acc[16] = 64 AGPR.
// B-frags from fragment-arranged Wua in global (lane-linear 1KB coalesced,
// L2-resident). A: k<256 xb bf16; k>=256 agg fp32 -> bf16 in-register.
__global__ __launch_bounds__(64)
void node_gemm_ln(const ushort* __restrict__ xb, const float* __restrict__ agg,
                  const ushort* __restrict__ Wua, const float* __restrict__ bupd,
                  const float* __restrict__ gamma, const float* __restrict__ beta,
                  float* __restrict__ out) {
    const int lane = threadIdx.x & 63;
    const int ml = lane & 15, kg = lane >> 4;
    const int nb = blockIdx.x * 16;
    const uint arow = (uint)(nb + ml) * DIM;          // 625*16 = 10000 exactly

    f32x4 acc[16];
#pragma unroll
    for (int nt = 0; nt < 16; ++nt) acc[nt] = (f32x4){0.f, 0.f, 0.f, 0.f};

#pragma unroll
    for (int kk = 0; kk < 8; ++kk) {                  // k in [0,256): A = xb
        bf16x8 a = *reinterpret_cast<const bf16x8*>(xb + arow + kk * 32 + kg * 8);
#pragma unroll
        for (int nt = 0; nt < 16; ++nt) {
            bf16x8 b = *reinterpret_cast<const bf16x8*>(Wua + kk * 8192 + nt * 512 + lane * 8);
            acc[nt] = __builtin_amdgcn_mfma_f32_16x16x32_bf16(a, b, acc[nt], 0, 0, 0);
        }
    }
#pragma unroll
    for (int kk = 0; kk < 8; ++kk) {                  // k in [256,512): A = agg (fp32)
        float4 f0 = *reinterpret_cast<const float4*>(agg + arow + kk * 32 + kg * 8);
        float4 f1 = *reinterpret_cast<const float4*>(agg + arow + kk * 32 + kg * 8 + 4);
        union { bf16x8 v; __hip_bfloat162 h2[4]; } u;
        u.h2[0] = __float22bfloat162_rn(make_float2(f0.x, f0.y));
        u.h2[1] = __float22bfloat162_rn(make_float2(f0.z, f0.w));
        u.h2[2] = __float22bfloat162_rn(make_float2(f1.x, f1.y));
        u.h2[3] = __float22bfloat162_rn(make_float2(f1.z, f1.w));
#pragma unroll
        for (int nt = 0; nt < 16; ++nt) {
            bf16x8 b = *reinterpret_cast<const bf16x8*>(Wua + 65536 + kk * 8192 + nt * 512 + lane * 8);
            acc[nt] = __builtin_amdgcn_mfma_f32_16x16x32_bf16(u.v, b, acc[nt], 0, 0, 0);
        }
    }

    // bias + relu + wave-local LayerNorm (rows kg*4+i live in 16 ml-lanes)
    float sum[4] = {0.f, 0.f, 0.f, 0.f}, ssq[4] = {0.f, 0.f, 0.f, 0.f};
#pragma unroll
    for (int nt = 0; nt < 16; ++nt) {
        const float bb = bupd[nt * 16 + ml];
#pragma unroll
        for (int i = 0; i < 4; ++i) {
            float v = acc[nt][i] + bb;
            v = v > 0.f ? v : 0.f;
            acc[nt][i] = v;
            sum[i] += v;
            ssq[i] += v * v;
        }
    }
#pragma unroll
    for (int m = 1; m < 16; m <<= 1) {
#pragma unroll
        for (int i = 0; i < 4; ++i) {
            sum[i] += __shfl_xor(sum[i], m);
            ssq[i] += __shfl_xor(ssq[i], m);
        }
    }
    float mu[4], rs[4];
#pragma unroll
    for (int i = 0; i < 4; ++i) {
        mu[i] = sum[i] * (1.f / 256.f);
        float var = ssq[i] * (1.f / 256.f) - mu[i] * mu[i];
        rs[i] = rsqrtf(var + LN_EPS);
    }
#pragma unroll
    for (int nt = 0; nt < 16; ++nt) {
        const int cc = nt * 16 + ml;
        const float g = gamma[cc], be = beta[cc];
#pragma unroll
        for (int i = 0; i < 4; ++i) {
            const int node = nb + kg * 4 + i;
            out[(size_t)node * DIM + cc] = (acc[nt][i] - mu[i]) * rs[i] * g + be;
        }
    }
}

extern "C" void kernel_launch(void* const* d_in, const int* in_sizes, int n_in,
                              void* d_out, int out_size, void* d_ws, size_t ws_size,
                              hipStream_t stream) {
    const float* x    = (const float*)d_in[0];
    const int*   eidx = (const int*)  d_in[1];
    const float* Wm   = (const float*)d_in[2];
    const float* bm   = (const float*)d_in[3];
    const float* Wu   = (const float*)d_in[4];
    const float* bu   = (const float*)d_in[5];
    const float* gam  = (const float*)d_in[6];
    const float* bet  = (const float*)d_in[7];
    float* out = (float*)d_out;

    char* ws = (char*)d_ws;
    float*  agg    = (float*) (ws);                    // 10,240,000 B
    ushort* xb     = (ushort*)(ws + 10240000);         //  5,120,000 B
    ushort* Wa     = (ushort*)(ws + 15360000);         //    262,144 B (edge W, arranged)
    ushort* Wua    = (ushort*)(ws + 15622144);         //    262,144 B (node W, arranged)
    int*    cnt    = (int*)   (ws + 15884288);         //     40,960 B
    int*    cursor = (int*)   (ws + 15925248);         //     40,960 B
    int*    srow   = (int*)   (ws + 15966208);         //  1,280,000 B
    int*    sdst   = (int*)   (ws + 17246208);         //  1,280,000 B

    hipMemsetAsync(agg, 0, (size_t)NNODES * DIM * sizeof(float), stream);
    hipMemsetAsync(cnt, 0, (size_t)NNODES * sizeof(int), stream);
    prep_cast<<<(NNODES * DIM / 4 + 255) / 256, 256, 0, stream>>>(x, xb, NNODES * DIM / 4);
    prep_wt<<<(2 * KTOT * DIM) / 256, 256, 0, stream>>>(Wm, Wu, Wa, Wua);
    hist_k<<<(NEDGES + 255) / 256, 256, 0, stream>>>(eidx, cnt);
    scan_k<<<1, 256, 0, stream>>>(cnt, cursor);
    scatter_k<<<(NEDGES + 255) / 256, 256, 0, stream>>>(eidx, cursor, srow, sdst);
    edge_gemm<<<2 * (NEDGES / 128), 256, 0, stream>>>(xb, srow, sdst, Wa, bm, agg);
    node_gemm_ln<<<NNODES / 16, 64, 0, stream>>>(xb, agg, Wua, bu, gam, bet, out);
}